// Round 2
// baseline (708.198 us; speedup 1.0000x reference)
//
#include <hip/hip_runtime.h>
#include <hip/hip_bf16.h>
#include <cstdint>

#define N_NODES 100000
#define N_EDGES 1600000
#define DIM 128            // HEADS * OUT_C = 4 * 32
#define GR 32              // rows per block in the dual GEMM

__device__ __forceinline__ float lrelu(float v) { return v >= 0.f ? v : 0.2f * v; }

// ---------------------------------------------------------------------------
// Dual projection: xl = x@Wl + bl  (to ws), xr = x@Wr + br  (to d_out, reused
// as scratch: wave d reads xr row d before overwriting it with out row d).
// tid<128 -> Wl column tid, tid>=128 -> Wr column tid-128. Each thread
// register-blocks GR=32 rows; x loads are thread-uniform float4 (scalarizes
// to s_load), W loads coalesce across the 128 columns.
// ---------------------------------------------------------------------------
__global__ __launch_bounds__(256) void gemm_dual(
    const float* __restrict__ x,
    const float* __restrict__ Wl, const float* __restrict__ bl,
    const float* __restrict__ Wr, const float* __restrict__ br,
    float* __restrict__ xl, float* __restrict__ xr) {
  const int col = threadIdx.x & 127;
  const int which = threadIdx.x >> 7;           // 0 -> l, 1 -> r
  const float* __restrict__ W = which ? Wr : Wl;
  const float* __restrict__ b = which ? br : bl;
  float* __restrict__ o = which ? xr : xl;
  const int row0 = blockIdx.x * GR;

  float acc[GR];
#pragma unroll
  for (int r = 0; r < GR; ++r) acc[r] = 0.f;

  for (int k = 0; k < DIM; k += 4) {
    const float w0 = W[(k + 0) * DIM + col];
    const float w1 = W[(k + 1) * DIM + col];
    const float w2 = W[(k + 2) * DIM + col];
    const float w3 = W[(k + 3) * DIM + col];
#pragma unroll
    for (int r = 0; r < GR; ++r) {
      const float4 xv = *reinterpret_cast<const float4*>(x + (size_t)(row0 + r) * DIM + k);
      acc[r] = fmaf(xv.x, w0, acc[r]);
      acc[r] = fmaf(xv.y, w1, acc[r]);
      acc[r] = fmaf(xv.z, w2, acc[r]);
      acc[r] = fmaf(xv.w, w3, acc[r]);
    }
  }
  const float bb = b[col];
#pragma unroll
  for (int r = 0; r < GR; ++r)
    o[(size_t)(row0 + r) * DIM + col] = acc[r] + bb;
}

// ---------------------------------------------------------------------------
// CSR build: histogram of dst, block-level exclusive scan, scatter src ids.
// ---------------------------------------------------------------------------
__global__ __launch_bounds__(256) void hist_kernel(const int* __restrict__ dst,
                                                   int* __restrict__ deg) {
  const int i = blockIdx.x * 256 + threadIdx.x;
  if (i < N_EDGES) atomicAdd(&deg[dst[i]], 1);
}

__global__ __launch_bounds__(1024) void scan1(const int* __restrict__ deg,
                                              int* __restrict__ excl,
                                              int* __restrict__ bsum) {
  __shared__ int tmp[1024];
  const int tid = threadIdx.x;
  const int gid = blockIdx.x * 1024 + tid;
  const int v = (gid < N_NODES) ? deg[gid] : 0;
  int xacc = v;
  tmp[tid] = v;
  __syncthreads();
  for (int offd = 1; offd < 1024; offd <<= 1) {
    const int t = (tid >= offd) ? tmp[tid - offd] : 0;
    __syncthreads();
    xacc += t;
    tmp[tid] = xacc;
    __syncthreads();
  }
  if (gid < N_NODES) excl[gid] = xacc - v;       // exclusive within block
  if (tid == 1023) bsum[blockIdx.x] = xacc;      // block total
}

__global__ __launch_bounds__(128) void scan2(int* __restrict__ bsum, int nb) {
  __shared__ int tmp[128];
  const int tid = threadIdx.x;
  const int v = (tid < nb) ? bsum[tid] : 0;
  int xacc = v;
  tmp[tid] = v;
  __syncthreads();
  for (int offd = 1; offd < 128; offd <<= 1) {
    const int t = (tid >= offd) ? tmp[tid - offd] : 0;
    __syncthreads();
    xacc += t;
    tmp[tid] = xacc;
    __syncthreads();
  }
  if (tid < nb) bsum[tid] = xacc - v;            // exclusive block offsets
}

__global__ __launch_bounds__(1024) void scan3(int* __restrict__ offs,
                                              const int* __restrict__ bsum,
                                              int* __restrict__ fill) {
  const int gid = blockIdx.x * 1024 + threadIdx.x;
  if (gid < N_NODES) {
    const int o = offs[gid] + bsum[blockIdx.x];
    offs[gid] = o;
    fill[gid] = o;
  }
  if (gid == N_NODES) offs[N_NODES] = N_EDGES;
}

__global__ __launch_bounds__(256) void scatter_kernel(const int* __restrict__ src,
                                                      const int* __restrict__ dst,
                                                      int* __restrict__ fill,
                                                      int* __restrict__ csr) {
  const int i = blockIdx.x * 256 + threadIdx.x;
  if (i < N_EDGES) {
    const int slot = atomicAdd(&fill[dst[i]], 1);
    csr[slot] = src[i];
  }
}

// ---------------------------------------------------------------------------
// One wave per destination node. Online softmax over {self loop} U {incoming
// edges}. Lane l owns channels 2l,2l+1 (one head per 16-lane group).
// Edge ids are vector-loaded 64-at-a-time and broadcast via shfl; the 512 B
// row gather is software-pipelined depth 2.
// xr lives in `out` (read before overwrite, same row only).
// ---------------------------------------------------------------------------
__global__ __launch_bounds__(256) void gat_node(
    const float* __restrict__ xl,
    const float* __restrict__ att, const float* __restrict__ bias,
    const int* __restrict__ offs, const int* __restrict__ csr,
    float* __restrict__ out) {
  const int wid = (blockIdx.x * 256 + threadIdx.x) >> 6;
  const int lane = threadIdx.x & 63;
  if (wid >= N_NODES) return;
  const int d = wid;

  const float2 a2 = reinterpret_cast<const float2*>(att)[lane];
  const float2 xr2 = reinterpret_cast<const float2*>(out + (size_t)d * DIM)[lane];
  const float2 xls = reinterpret_cast<const float2*>(xl + (size_t)d * DIM)[lane];

  // self loop initializes the online softmax state
  float e = lrelu(xls.x + xr2.x) * a2.x + lrelu(xls.y + xr2.y) * a2.y;
  e += __shfl_xor(e, 1);
  e += __shfl_xor(e, 2);
  e += __shfl_xor(e, 4);
  e += __shfl_xor(e, 8);             // 16-lane head group now holds its score
  float mrun = e;                    // running max
  float lrun = 1.f;                  // running denom
  float accx = xls.x, accy = xls.y;  // running weighted message sum

  const int beg = offs[d];
  const int end = offs[d + 1];

  for (int cbase = beg; cbase < end; cbase += 64) {
    const int idx = cbase + lane;
    const int sv = csr[idx < end ? idx : end - 1];   // 64 edge ids, coalesced
    const int cnt = min(64, end - cbase);

    // depth-2 pipeline: gather for j+1 in flight while processing j
    int s0 = __shfl(sv, 0);
    float2 xv = reinterpret_cast<const float2*>(xl + (size_t)s0 * DIM)[lane];
    for (int j = 0; j < cnt; ++j) {
      const float2 xc = xv;
      if (j + 1 < cnt) {
        const int s1 = __shfl(sv, j + 1);
        xv = reinterpret_cast<const float2*>(xl + (size_t)s1 * DIM)[lane];
      }
      float ek = lrelu(xc.x + xr2.x) * a2.x + lrelu(xc.y + xr2.y) * a2.y;
      ek += __shfl_xor(ek, 1);
      ek += __shfl_xor(ek, 2);
      ek += __shfl_xor(ek, 4);
      ek += __shfl_xor(ek, 8);
      const float mn = fmaxf(mrun, ek);
      const float sc = __expf(mrun - mn);
      const float wgt = __expf(ek - mn);
      lrun = lrun * sc + wgt;
      accx = fmaf(wgt, xc.x, accx * sc);
      accy = fmaf(wgt, xc.y, accy * sc);
      mrun = mn;
    }
  }

  const float2 b2 = reinterpret_cast<const float2*>(bias)[lane];
  float2 o;
  o.x = accx / lrun + b2.x;
  o.y = accy / lrun + b2.y;
  reinterpret_cast<float2*>(out + (size_t)d * DIM)[lane] = o;
}

// ---------------------------------------------------------------------------
extern "C" void kernel_launch(void* const* d_in, const int* in_sizes, int n_in,
                              void* d_out, int out_size, void* d_ws, size_t ws_size,
                              hipStream_t stream) {
  const float* x    = (const float*)d_in[0];
  const float* Wl   = (const float*)d_in[1];
  const float* bl   = (const float*)d_in[2];
  const float* Wr   = (const float*)d_in[3];
  const float* br   = (const float*)d_in[4];
  const float* att  = (const float*)d_in[5];
  const float* bias = (const float*)d_in[6];
  const int* src    = (const int*)d_in[7];
  const int* dst    = (const int*)d_in[8];
  float* out = (float*)d_out;

  char* w = (char*)d_ws;
  size_t off = 0;
  auto alloc = [&](size_t bytes) -> void* {
    void* p = w + off;
    off = (off + bytes + 255) & ~(size_t)255;
    return p;
  };
  float* xl = (float*)alloc((size_t)N_NODES * DIM * 4);   // 51.2 MB
  int* deg  = (int*)alloc((size_t)N_NODES * 4);
  int* offs = (int*)alloc((size_t)(N_NODES + 1) * 4);
  int* fill = (int*)alloc((size_t)N_NODES * 4);
  int* bsum = (int*)alloc(1024);
  int* csr  = (int*)alloc((size_t)N_EDGES * 4);           // 6.4 MB
  float* xr = out;                                        // scratch alias (safe: see gat_node)

  const int nscan_blocks = (N_NODES + 1023) / 1024;   // 98

  hipMemsetAsync(deg, 0, (size_t)N_NODES * 4, stream);
  gemm_dual<<<N_NODES / GR, 256, 0, stream>>>(x, Wl, bl, Wr, br, xl, xr);
  hist_kernel<<<(N_EDGES + 255) / 256, 256, 0, stream>>>(dst, deg);
  scan1<<<nscan_blocks, 1024, 0, stream>>>(deg, offs, bsum);
  scan2<<<1, 128, 0, stream>>>(bsum, nscan_blocks);
  scan3<<<nscan_blocks, 1024, 0, stream>>>(offs, bsum, fill);
  scatter_kernel<<<(N_EDGES + 255) / 256, 256, 0, stream>>>(src, dst, fill, csr);
  gat_node<<<(N_NODES * 64 + 255) / 256, 256, 0, stream>>>(xl, att, bias, offs, csr, out);
}

// Round 5
// 545.771 us; speedup vs baseline: 1.2976x; 1.2976x over previous
//
#include <hip/hip_runtime.h>
#include <hip/hip_bf16.h>
#include <cstdint>

#define N_NODES 100000
#define N_EDGES 1600000
#define DIM 128            // HEADS * OUT_C = 4 * 32
#define GR 32              // rows per block in the dual GEMM

__device__ __forceinline__ float lrelu(float v) { return v >= 0.f ? v : 0.2f * v; }

// ---------------------------------------------------------------------------
// Dual projection: xl = x@Wl + bl (ws), xr = x@Wr + br (d_out as scratch;
// wave d reads xr row d before overwriting it with out row d).
// LDS-staged tile GEMM: 32 rows x 256 cols (Wl cols 0-127 | Wr cols 0-127).
// Thread (cg,rg): cg=tid&63 -> 4 cols of one W, rg=tid>>6 -> 8 rows.
// x tile staged in LDS via coalesced float4 loads; reads are wave-uniform
// broadcasts (ds_read_b128, conflict-free). W loads coalesce as b128.
// acc[8][4]=32 VGPR held live -> VALU(fma)-bound, ~42us roofline.
// ---------------------------------------------------------------------------
__global__ __launch_bounds__(256) void gemm_dual(
    const float* __restrict__ x,
    const float* __restrict__ Wl, const float* __restrict__ bl,
    const float* __restrict__ Wr, const float* __restrict__ br,
    float* __restrict__ xl, float* __restrict__ xr) {
  __shared__ float xs[GR][DIM];          // 16 KB
  const int tid = threadIdx.x;
  const int row0 = blockIdx.x * GR;

  // stage x tile: 32 rows * 32 float4 = 1024 float4, 4 per thread, coalesced
#pragma unroll
  for (int i = 0; i < 4; ++i) {
    const int idx = i * 256 + tid;       // 0..1023
    const int r = idx >> 5;              // 32 float4 per row
    const int c4 = idx & 31;
    const float4 v = *reinterpret_cast<const float4*>(
        x + (size_t)(row0 + r) * DIM + c4 * 4);
    *reinterpret_cast<float4*>(&xs[r][c4 * 4]) = v;
  }
  __syncthreads();

  const int cg = tid & 63;               // 0..63 column group
  const int rg = tid >> 6;               // 0..3 row group
  const int which = cg >> 5;             // 0 -> Wl, 1 -> Wr
  const int col0 = (cg & 31) * 4;        // 0..124
  const float* __restrict__ W = which ? Wr : Wl;
  const float* __restrict__ b = which ? br : bl;
  float* __restrict__ o = which ? xr : xl;
  const int r0 = rg * 8;

  float acc[8][4];
#pragma unroll
  for (int r = 0; r < 8; ++r)
#pragma unroll
    for (int c = 0; c < 4; ++c) acc[r][c] = 0.f;

  for (int kb = 0; kb < DIM; kb += 4) {
    float4 w0 = *reinterpret_cast<const float4*>(W + (kb + 0) * DIM + col0);
    float4 w1 = *reinterpret_cast<const float4*>(W + (kb + 1) * DIM + col0);
    float4 w2 = *reinterpret_cast<const float4*>(W + (kb + 2) * DIM + col0);
    float4 w3 = *reinterpret_cast<const float4*>(W + (kb + 3) * DIM + col0);
#pragma unroll
    for (int r = 0; r < 8; ++r) {
      const float4 xv = *reinterpret_cast<const float4*>(&xs[r0 + r][kb]);
      acc[r][0] = fmaf(xv.x, w0.x, acc[r][0]);
      acc[r][1] = fmaf(xv.x, w0.y, acc[r][1]);
      acc[r][2] = fmaf(xv.x, w0.z, acc[r][2]);
      acc[r][3] = fmaf(xv.x, w0.w, acc[r][3]);
      acc[r][0] = fmaf(xv.y, w1.x, acc[r][0]);
      acc[r][1] = fmaf(xv.y, w1.y, acc[r][1]);
      acc[r][2] = fmaf(xv.y, w1.z, acc[r][2]);
      acc[r][3] = fmaf(xv.y, w1.w, acc[r][3]);
      acc[r][0] = fmaf(xv.z, w2.x, acc[r][0]);
      acc[r][1] = fmaf(xv.z, w2.y, acc[r][1]);
      acc[r][2] = fmaf(xv.z, w2.z, acc[r][2]);
      acc[r][3] = fmaf(xv.z, w2.w, acc[r][3]);
      acc[r][0] = fmaf(xv.w, w3.x, acc[r][0]);
      acc[r][1] = fmaf(xv.w, w3.y, acc[r][1]);
      acc[r][2] = fmaf(xv.w, w3.z, acc[r][2]);
      acc[r][3] = fmaf(xv.w, w3.w, acc[r][3]);
    }
  }

  const float4 bb = *reinterpret_cast<const float4*>(b + col0);
#pragma unroll
  for (int r = 0; r < 8; ++r) {
    float4 ov;
    ov.x = acc[r][0] + bb.x;
    ov.y = acc[r][1] + bb.y;
    ov.z = acc[r][2] + bb.z;
    ov.w = acc[r][3] + bb.w;
    *reinterpret_cast<float4*>(o + (size_t)(row0 + r0 + r) * DIM + col0) = ov;
  }
}

// ---------------------------------------------------------------------------
// CSR build: histogram of dst, block-level exclusive scan, scatter src ids.
// ---------------------------------------------------------------------------
__global__ __launch_bounds__(256) void hist_kernel(const int* __restrict__ dst,
                                                   int* __restrict__ deg) {
  const int i = blockIdx.x * 256 + threadIdx.x;
  if (i < N_EDGES) atomicAdd(&deg[dst[i]], 1);
}

__global__ __launch_bounds__(1024) void scan1(const int* __restrict__ deg,
                                              int* __restrict__ excl,
                                              int* __restrict__ bsum) {
  __shared__ int tmp[1024];
  const int tid = threadIdx.x;
  const int gid = blockIdx.x * 1024 + tid;
  const int v = (gid < N_NODES) ? deg[gid] : 0;
  int xacc = v;
  tmp[tid] = v;
  __syncthreads();
  for (int offd = 1; offd < 1024; offd <<= 1) {
    const int t = (tid >= offd) ? tmp[tid - offd] : 0;
    __syncthreads();
    xacc += t;
    tmp[tid] = xacc;
    __syncthreads();
  }
  if (gid < N_NODES) excl[gid] = xacc - v;       // exclusive within block
  if (tid == 1023) bsum[blockIdx.x] = xacc;      // block total
}

__global__ __launch_bounds__(128) void scan2(int* __restrict__ bsum, int nb) {
  __shared__ int tmp[128];
  const int tid = threadIdx.x;
  const int v = (tid < nb) ? bsum[tid] : 0;
  int xacc = v;
  tmp[tid] = v;
  __syncthreads();
  for (int offd = 1; offd < 128; offd <<= 1) {
    const int t = (tid >= offd) ? tmp[tid - offd] : 0;
    __syncthreads();
    xacc += t;
    tmp[tid] = xacc;
    __syncthreads();
  }
  if (tid < nb) bsum[tid] = xacc - v;            // exclusive block offsets
}

__global__ __launch_bounds__(1024) void scan3(int* __restrict__ offs,
                                              const int* __restrict__ bsum,
                                              int* __restrict__ fill) {
  const int gid = blockIdx.x * 1024 + threadIdx.x;
  if (gid < N_NODES) {
    const int o = offs[gid] + bsum[blockIdx.x];
    offs[gid] = o;
    fill[gid] = o;
  }
  if (gid == N_NODES) offs[N_NODES] = N_EDGES;
}

__global__ __launch_bounds__(256) void scatter_kernel(const int* __restrict__ src,
                                                      const int* __restrict__ dst,
                                                      int* __restrict__ fill,
                                                      int* __restrict__ csr) {
  const int i = blockIdx.x * 256 + threadIdx.x;
  if (i < N_EDGES) {
    const int slot = atomicAdd(&fill[dst[i]], 1);
    csr[slot] = src[i];
  }
}

// ---------------------------------------------------------------------------
// One wave per destination node. Online softmax over {self loop} U {incoming
// edges}. Lane l owns channels 2l,2l+1 (one head per 16-lane group).
// Edge ids vector-loaded 64-at-a-time (coalesced) and broadcast via shfl;
// the 512 B row gather is software-pipelined depth 4 (register rotation —
// no runtime-indexed arrays, so no scratch).
// xr lives in `out` (read before overwrite, same row only).
// ---------------------------------------------------------------------------
__global__ __launch_bounds__(256) void gat_node(
    const float* __restrict__ xl,
    const float* __restrict__ att, const float* __restrict__ bias,
    const int* __restrict__ offs, const int* __restrict__ csr,
    float* __restrict__ out) {
  const int wid = (blockIdx.x * 256 + threadIdx.x) >> 6;
  const int lane = threadIdx.x & 63;
  if (wid >= N_NODES) return;
  const int d = wid;

  const float2 a2 = reinterpret_cast<const float2*>(att)[lane];
  const float2 xr2 = reinterpret_cast<const float2*>(out + (size_t)d * DIM)[lane];
  const float2 xls = reinterpret_cast<const float2*>(xl + (size_t)d * DIM)[lane];

  // self loop initializes the online softmax state
  float e = lrelu(xls.x + xr2.x) * a2.x + lrelu(xls.y + xr2.y) * a2.y;
  e += __shfl_xor(e, 1);
  e += __shfl_xor(e, 2);
  e += __shfl_xor(e, 4);
  e += __shfl_xor(e, 8);             // 16-lane head group now holds its score
  float mrun = e;                    // running max
  float lrun = 1.f;                  // running denom
  float accx = xls.x, accy = xls.y;  // running weighted message sum

  const int beg = offs[d];
  const int end = offs[d + 1];

  for (int cbase = beg; cbase < end; cbase += 64) {
    const int idx = cbase + lane;
    const int sv = csr[idx < end ? idx : end - 1];   // 64 edge ids, coalesced
    const int cnt = min(64, end - cbase);

    // depth-4 pipeline via register rotation
    auto ldrow = [&](int j) -> float2 {
      const int s = __shfl(sv, j < cnt ? j : 0);
      return reinterpret_cast<const float2*>(xl + (size_t)s * DIM)[lane];
    };
    float2 A = ldrow(0);
    float2 B = ldrow(1);
    float2 C = ldrow(2);
    float2 D = ldrow(3);

    for (int j = 0; j < cnt; ++j) {
      const float2 xc = A;
      A = B; B = C; C = D;
      if (j + 4 < cnt) {
        const int s = __shfl(sv, j + 4);
        D = reinterpret_cast<const float2*>(xl + (size_t)s * DIM)[lane];
      }
      float ek = lrelu(xc.x + xr2.x) * a2.x + lrelu(xc.y + xr2.y) * a2.y;
      ek += __shfl_xor(ek, 1);
      ek += __shfl_xor(ek, 2);
      ek += __shfl_xor(ek, 4);
      ek += __shfl_xor(ek, 8);
      const float mn = fmaxf(mrun, ek);
      const float sc = __expf(mrun - mn);
      const float wgt = __expf(ek - mn);
      lrun = lrun * sc + wgt;
      accx = fmaf(wgt, xc.x, accx * sc);
      accy = fmaf(wgt, xc.y, accy * sc);
      mrun = mn;
    }
  }

  const float2 b2 = reinterpret_cast<const float2*>(bias)[lane];
  float2 o;
  o.x = accx / lrun + b2.x;
  o.y = accy / lrun + b2.y;
  reinterpret_cast<float2*>(out + (size_t)d * DIM)[lane] = o;
}

// ---------------------------------------------------------------------------
extern "C" void kernel_launch(void* const* d_in, const int* in_sizes, int n_in,
                              void* d_out, int out_size, void* d_ws, size_t ws_size,
                              hipStream_t stream) {
  const float* x    = (const float*)d_in[0];
  const float* Wl   = (const float*)d_in[1];
  const float* bl   = (const float*)d_in[2];
  const float* Wr   = (const float*)d_in[3];
  const float* br   = (const float*)d_in[4];
  const float* att  = (const float*)d_in[5];
  const float* bias = (const float*)d_in[6];
  const int* src    = (const int*)d_in[7];
  const int* dst    = (const int*)d_in[8];
  float* out = (float*)d_out;

  char* w = (char*)d_ws;
  size_t off = 0;
  auto alloc = [&](size_t bytes) -> void* {
    void* p = w + off;
    off = (off + bytes + 255) & ~(size_t)255;
    return p;
  };
  float* xl = (float*)alloc((size_t)N_NODES * DIM * 4);   // 51.2 MB
  int* deg  = (int*)alloc((size_t)N_NODES * 4);
  int* offs = (int*)alloc((size_t)(N_NODES + 1) * 4);
  int* fill = (int*)alloc((size_t)N_NODES * 4);
  int* bsum = (int*)alloc(1024);
  int* csr  = (int*)alloc((size_t)N_EDGES * 4);           // 6.4 MB
  float* xr = out;                                        // scratch alias (safe: see gat_node)

  const int nscan_blocks = (N_NODES + 1023) / 1024;   // 98

  hipMemsetAsync(deg, 0, (size_t)N_NODES * 4, stream);
  gemm_dual<<<N_NODES / GR, 256, 0, stream>>>(x, Wl, bl, Wr, br, xl, xr);
  hist_kernel<<<(N_EDGES + 255) / 256, 256, 0, stream>>>(dst, deg);
  scan1<<<nscan_blocks, 1024, 0, stream>>>(deg, offs, bsum);
  scan2<<<1, 128, 0, stream>>>(bsum, nscan_blocks);
  scan3<<<nscan_blocks, 1024, 0, stream>>>(offs, bsum, fill);
  scatter_kernel<<<(N_EDGES + 255) / 256, 256, 0, stream>>>(src, dst, fill, csr);
  gat_node<<<(N_NODES * 64 + 255) / 256, 256, 0, stream>>>(xl, att, bias, offs, csr, out);
}

// Round 6
// 508.264 us; speedup vs baseline: 1.3934x; 1.0738x over previous
//
#include <hip/hip_runtime.h>
#include <hip/hip_bf16.h>
#include <cstdint>

#define N_NODES 100000
#define N_EDGES 1600000
#define DIM 128            // HEADS * OUT_C = 4 * 32
#define GR 32              // rows per block in the dual GEMM

__device__ __forceinline__ float lrelu(float v) { return v >= 0.f ? v : 0.2f * v; }
// branch-free exact LeakyReLU(0.2): v>=0 -> v, v<0 -> 0.2v
__device__ __forceinline__ float lr(float v) { return fmaxf(v, 0.2f * v); }

// ---------------------------------------------------------------------------
// Dual projection: xl = x@Wl + bl (ws), xr = x@Wr + br (d_out as scratch;
// wave d reads xr row d before overwriting it with out row d).
// LDS-staged tile GEMM: 32 rows x 256 cols (Wl cols 0-127 | Wr cols 0-127).
// Thread (cg,rg): cg=tid&63 -> 4 cols of one W, rg=tid>>6 -> 8 rows.
// x tile staged in LDS via coalesced float4 loads; reads are wave-uniform
// broadcasts (ds_read_b128, conflict-free). W loads coalesce as b128.
// acc[8][4]=32 VGPR held live -> VALU(fma)-bound.
// Measured R5: out of top-5 (<173us). Leave unchanged for attribution.
// ---------------------------------------------------------------------------
__global__ __launch_bounds__(256) void gemm_dual(
    const float* __restrict__ x,
    const float* __restrict__ Wl, const float* __restrict__ bl,
    const float* __restrict__ Wr, const float* __restrict__ br,
    float* __restrict__ xl, float* __restrict__ xr) {
  __shared__ float xs[GR][DIM];          // 16 KB
  const int tid = threadIdx.x;
  const int row0 = blockIdx.x * GR;

  // stage x tile: 32 rows * 32 float4 = 1024 float4, 4 per thread, coalesced
#pragma unroll
  for (int i = 0; i < 4; ++i) {
    const int idx = i * 256 + tid;       // 0..1023
    const int r = idx >> 5;              // 32 float4 per row
    const int c4 = idx & 31;
    const float4 v = *reinterpret_cast<const float4*>(
        x + (size_t)(row0 + r) * DIM + c4 * 4);
    *reinterpret_cast<float4*>(&xs[r][c4 * 4]) = v;
  }
  __syncthreads();

  const int cg = tid & 63;               // 0..63 column group
  const int rg = tid >> 6;               // 0..3 row group
  const int which = cg >> 5;             // 0 -> Wl, 1 -> Wr
  const int col0 = (cg & 31) * 4;        // 0..124
  const float* __restrict__ W = which ? Wr : Wl;
  const float* __restrict__ b = which ? br : bl;
  float* __restrict__ o = which ? xr : xl;
  const int r0 = rg * 8;

  float acc[8][4];
#pragma unroll
  for (int r = 0; r < 8; ++r)
#pragma unroll
    for (int c = 0; c < 4; ++c) acc[r][c] = 0.f;

  for (int kb = 0; kb < DIM; kb += 4) {
    float4 w0 = *reinterpret_cast<const float4*>(W + (kb + 0) * DIM + col0);
    float4 w1 = *reinterpret_cast<const float4*>(W + (kb + 1) * DIM + col0);
    float4 w2 = *reinterpret_cast<const float4*>(W + (kb + 2) * DIM + col0);
    float4 w3 = *reinterpret_cast<const float4*>(W + (kb + 3) * DIM + col0);
#pragma unroll
    for (int r = 0; r < 8; ++r) {
      const float4 xv = *reinterpret_cast<const float4*>(&xs[r0 + r][kb]);
      acc[r][0] = fmaf(xv.x, w0.x, acc[r][0]);
      acc[r][1] = fmaf(xv.x, w0.y, acc[r][1]);
      acc[r][2] = fmaf(xv.x, w0.z, acc[r][2]);
      acc[r][3] = fmaf(xv.x, w0.w, acc[r][3]);
      acc[r][0] = fmaf(xv.y, w1.x, acc[r][0]);
      acc[r][1] = fmaf(xv.y, w1.y, acc[r][1]);
      acc[r][2] = fmaf(xv.y, w1.z, acc[r][2]);
      acc[r][3] = fmaf(xv.y, w1.w, acc[r][3]);
      acc[r][0] = fmaf(xv.z, w2.x, acc[r][0]);
      acc[r][1] = fmaf(xv.z, w2.y, acc[r][1]);
      acc[r][2] = fmaf(xv.z, w2.z, acc[r][2]);
      acc[r][3] = fmaf(xv.z, w2.w, acc[r][3]);
      acc[r][0] = fmaf(xv.w, w3.x, acc[r][0]);
      acc[r][1] = fmaf(xv.w, w3.y, acc[r][1]);
      acc[r][2] = fmaf(xv.w, w3.z, acc[r][2]);
      acc[r][3] = fmaf(xv.w, w3.w, acc[r][3]);
    }
  }

  const float4 bb = *reinterpret_cast<const float4*>(b + col0);
#pragma unroll
  for (int r = 0; r < 8; ++r) {
    float4 ov;
    ov.x = acc[r][0] + bb.x;
    ov.y = acc[r][1] + bb.y;
    ov.z = acc[r][2] + bb.z;
    ov.w = acc[r][3] + bb.w;
    *reinterpret_cast<float4*>(o + (size_t)(row0 + r0 + r) * DIM + col0) = ov;
  }
}

// ---------------------------------------------------------------------------
// CSR build: histogram of dst, block-level exclusive scan, scatter src ids.
// ---------------------------------------------------------------------------
__global__ __launch_bounds__(256) void hist_kernel(const int* __restrict__ dst,
                                                   int* __restrict__ deg) {
  const int i = blockIdx.x * 256 + threadIdx.x;
  if (i < N_EDGES) atomicAdd(&deg[dst[i]], 1);
}

__global__ __launch_bounds__(1024) void scan1(const int* __restrict__ deg,
                                              int* __restrict__ excl,
                                              int* __restrict__ bsum) {
  __shared__ int tmp[1024];
  const int tid = threadIdx.x;
  const int gid = blockIdx.x * 1024 + tid;
  const int v = (gid < N_NODES) ? deg[gid] : 0;
  int xacc = v;
  tmp[tid] = v;
  __syncthreads();
  for (int offd = 1; offd < 1024; offd <<= 1) {
    const int t = (tid >= offd) ? tmp[tid - offd] : 0;
    __syncthreads();
    xacc += t;
    tmp[tid] = xacc;
    __syncthreads();
  }
  if (gid < N_NODES) excl[gid] = xacc - v;       // exclusive within block
  if (tid == 1023) bsum[blockIdx.x] = xacc;      // block total
}

__global__ __launch_bounds__(128) void scan2(int* __restrict__ bsum, int nb) {
  __shared__ int tmp[128];
  const int tid = threadIdx.x;
  const int v = (tid < nb) ? bsum[tid] : 0;
  int xacc = v;
  tmp[tid] = v;
  __syncthreads();
  for (int offd = 1; offd < 128; offd <<= 1) {
    const int t = (tid >= offd) ? tmp[tid - offd] : 0;
    __syncthreads();
    xacc += t;
    tmp[tid] = xacc;
    __syncthreads();
  }
  if (tid < nb) bsum[tid] = xacc - v;            // exclusive block offsets
}

__global__ __launch_bounds__(1024) void scan3(int* __restrict__ offs,
                                              const int* __restrict__ bsum,
                                              int* __restrict__ fill) {
  const int gid = blockIdx.x * 1024 + threadIdx.x;
  if (gid < N_NODES) {
    const int o = offs[gid] + bsum[blockIdx.x];
    offs[gid] = o;
    fill[gid] = o;
  }
  if (gid == N_NODES) offs[N_NODES] = N_EDGES;
}

__global__ __launch_bounds__(256) void scatter_kernel(const int* __restrict__ src,
                                                      const int* __restrict__ dst,
                                                      int* __restrict__ fill,
                                                      int* __restrict__ csr) {
  const int i = blockIdx.x * 256 + threadIdx.x;
  if (i < N_EDGES) {
    const int slot = atomicAdd(&fill[dst[i]], 1);
    csr[slot] = src[i];
  }
}

// ---------------------------------------------------------------------------
// One wave per destination node, 2-way edge packing:
// lane owns float4 (4 channels), i=lane&31 -> channels 4i..4i+3, so 32 lanes
// cover a 128-ch row and the wave processes TWO edges per iteration
// (half0 = lanes 0-31: edges [0,nh) + self loop; half1 = lanes 32-63:
// edges [nh,cnt)). Each half keeps an independent online-softmax state
// (m, l, acc4); merged at the end via shfl_xor(.,32):
//   m* = max(m0,m1); l* = l0 e^{m0-m*} + l1 e^{m1-m*}; acc* likewise.
// Head = 32 ch = 8 lanes -> score reduce is 3 shfl_xor (1,2,4).
// Invalid slots score -2e30 (< -1e30 empty-state init -> exp underflows to 0;
// explicit w=0 select as well). Gather pipelined depth-3 (named regs).
// xr lives in `out` (read before overwrite, same row only).
// ---------------------------------------------------------------------------
__global__ __launch_bounds__(256) void gat_node(
    const float* __restrict__ xl,
    const float* __restrict__ att, const float* __restrict__ bias,
    const int* __restrict__ offs, const int* __restrict__ csr,
    float* __restrict__ out) {
  const int wid = (blockIdx.x * 256 + threadIdx.x) >> 6;
  const int lane = threadIdx.x & 63;
  if (wid >= N_NODES) return;
  const int d = wid;
  const int i = lane & 31;           // channel-group index within row
  const int c0 = i * 4;              // channel base
  const bool h0 = lane < 32;

  const float4 a4  = *reinterpret_cast<const float4*>(att + c0);
  const float4 xr4 = *reinterpret_cast<const float4*>(out + (size_t)d * DIM + c0);
  const float4 xls = *reinterpret_cast<const float4*>(xl + (size_t)d * DIM + c0);

  // self-loop score (identical in both halves; only half0 keeps it)
  float p = lr(xls.x + xr4.x) * a4.x + lr(xls.y + xr4.y) * a4.y
          + lr(xls.z + xr4.z) * a4.z + lr(xls.w + xr4.w) * a4.w;
  p += __shfl_xor(p, 1);
  p += __shfl_xor(p, 2);
  p += __shfl_xor(p, 4);             // 8-lane head group holds its score

  float m = h0 ? p : -1e30f;         // running max
  float l = h0 ? 1.f : 0.f;          // running denom
  float4 acc;                        // running weighted message sum
  acc.x = h0 ? xls.x : 0.f;
  acc.y = h0 ? xls.y : 0.f;
  acc.z = h0 ? xls.z : 0.f;
  acc.w = h0 ? xls.w : 0.f;

  const int beg = offs[d];
  const int end = offs[d + 1];

  for (int cbase = beg; cbase < end; cbase += 64) {
    const int idx = cbase + lane;
    const int sv = csr[idx < end ? idx : end - 1];   // 64 edge ids, coalesced
    const int cnt = min(64, end - cbase);
    const int nh = (cnt + 1) >> 1;   // iterations; half0 does [0,nh), half1 [nh,cnt)

    auto fetch = [&](int j) -> float4 {
      const int jj = j < nh ? j : nh - 1;            // clamp prefetch overrun
      const int pos = h0 ? jj : nh + jj;             // <= 63
      const int s = __shfl(sv, pos);                 // per-lane source lane
      return *reinterpret_cast<const float4*>(xl + (size_t)s * DIM + c0);
    };
    float4 A = fetch(0);
    float4 B = fetch(1);
    float4 C = fetch(2);

    for (int j = 0; j < nh; ++j) {
      const float4 xv = A;
      A = B; B = C;
      if (j + 3 < nh) C = fetch(j + 3);
      const int e = h0 ? j : nh + j;
      const bool valid = e < cnt;                    // half0 always valid

      float ek = lr(xv.x + xr4.x) * a4.x + lr(xv.y + xr4.y) * a4.y
               + lr(xv.z + xr4.z) * a4.z + lr(xv.w + xr4.w) * a4.w;
      ek += __shfl_xor(ek, 1);
      ek += __shfl_xor(ek, 2);
      ek += __shfl_xor(ek, 4);
      ek = valid ? ek : -2e30f;

      const float mn = fmaxf(m, ek);
      const float sc = __expf(m - mn);
      float w = __expf(ek - mn);
      w = valid ? w : 0.f;
      l = l * sc + w;
      acc.x = fmaf(acc.x, sc, w * xv.x);
      acc.y = fmaf(acc.y, sc, w * xv.y);
      acc.z = fmaf(acc.z, sc, w * xv.z);
      acc.w = fmaf(acc.w, sc, w * xv.w);
      m = mn;
    }
  }

  // merge the two halves' online-softmax states
  const float mo = __shfl_xor(m, 32);
  const float lo_ = __shfl_xor(l, 32);
  float4 ao;
  ao.x = __shfl_xor(acc.x, 32);
  ao.y = __shfl_xor(acc.y, 32);
  ao.z = __shfl_xor(acc.z, 32);
  ao.w = __shfl_xor(acc.w, 32);
  const float ms = fmaxf(m, mo);
  const float ws = __expf(m - ms);
  const float wo = __expf(mo - ms);
  const float lm = l * ws + lo_ * wo;    // >= e^{self-m*} > 0

  if (h0) {
    const float4 b4 = *reinterpret_cast<const float4*>(bias + c0);
    float4 o;
    o.x = (acc.x * ws + ao.x * wo) / lm + b4.x;
    o.y = (acc.y * ws + ao.y * wo) / lm + b4.y;
    o.z = (acc.z * ws + ao.z * wo) / lm + b4.z;
    o.w = (acc.w * ws + ao.w * wo) / lm + b4.w;
    *reinterpret_cast<float4*>(out + (size_t)d * DIM + c0) = o;
  }
}

// ---------------------------------------------------------------------------
extern "C" void kernel_launch(void* const* d_in, const int* in_sizes, int n_in,
                              void* d_out, int out_size, void* d_ws, size_t ws_size,
                              hipStream_t stream) {
  const float* x    = (const float*)d_in[0];
  const float* Wl   = (const float*)d_in[1];
  const float* bl   = (const float*)d_in[2];
  const float* Wr   = (const float*)d_in[3];
  const float* br   = (const float*)d_in[4];
  const float* att  = (const float*)d_in[5];
  const float* bias = (const float*)d_in[6];
  const int* src    = (const int*)d_in[7];
  const int* dst    = (const int*)d_in[8];
  float* out = (float*)d_out;

  char* w = (char*)d_ws;
  size_t off = 0;
  auto alloc = [&](size_t bytes) -> void* {
    void* p = w + off;
    off = (off + bytes + 255) & ~(size_t)255;
    return p;
  };
  float* xl = (float*)alloc((size_t)N_NODES * DIM * 4);   // 51.2 MB
  int* deg  = (int*)alloc((size_t)N_NODES * 4);
  int* offs = (int*)alloc((size_t)(N_NODES + 1) * 4);
  int* fill = (int*)alloc((size_t)N_NODES * 4);
  int* bsum = (int*)alloc(1024);
  int* csr  = (int*)alloc((size_t)N_EDGES * 4);           // 6.4 MB
  float* xr = out;                                        // scratch alias (safe: see gat_node)

  const int nscan_blocks = (N_NODES + 1023) / 1024;   // 98

  hipMemsetAsync(deg, 0, (size_t)N_NODES * 4, stream);
  gemm_dual<<<N_NODES / GR, 256, 0, stream>>>(x, Wl, bl, Wr, br, xl, xr);
  hist_kernel<<<(N_EDGES + 255) / 256, 256, 0, stream>>>(dst, deg);
  scan1<<<nscan_blocks, 1024, 0, stream>>>(deg, offs, bsum);
  scan2<<<1, 128, 0, stream>>>(bsum, nscan_blocks);
  scan3<<<nscan_blocks, 1024, 0, stream>>>(offs, bsum, fill);
  scatter_kernel<<<(N_EDGES + 255) / 256, 256, 0, stream>>>(src, dst, fill, csr);
  gat_node<<<(N_NODES * 64 + 255) / 256, 256, 0, stream>>>(xl, att, bias, offs, csr, out);
}

// Round 8
// 487.820 us; speedup vs baseline: 1.4518x; 1.0419x over previous
//
#include <hip/hip_runtime.h>
#include <hip/hip_bf16.h>
#include <cstdint>

#define N_NODES 100000
#define N_EDGES 1600000
#define DIM 128            // HEADS * OUT_C = 4 * 32
#define GR 32              // rows per block in the dual GEMM
#define GEMM_BLOCKS (N_NODES / GR)          // 3125
#define HIST_BLOCKS ((N_EDGES + 255) / 256) // 6250

// branch-free exact LeakyReLU(0.2): v>=0 -> v, v<0 -> 0.2v
__device__ __forceinline__ float lr(float v) { return fmaxf(v, 0.2f * v); }

// ---------------------------------------------------------------------------
// Fused: dual projection + dst histogram (data-independent, co-scheduled).
// Blocks [0, GEMM_BLOCKS): xl = x@Wl + bl (ws), xr = x@Wr + br (d_out as
//   scratch; gat wave d reads xr row d before overwriting it with out row d).
//   LDS-staged 32x256 tile; acc[8][4] live in VGPRs; VALU-bound.
// Blocks [GEMM_BLOCKS, +HIST_BLOCKS): deg histogram of dst (int atomics) —
//   hides under the VALU-bound GEMM blocks instead of serializing after.
// ---------------------------------------------------------------------------
__global__ __launch_bounds__(256) void gemm_hist(
    const float* __restrict__ x,
    const float* __restrict__ Wl, const float* __restrict__ bl,
    const float* __restrict__ Wr, const float* __restrict__ br,
    float* __restrict__ xl, float* __restrict__ xr,
    const int* __restrict__ dst, int* __restrict__ deg) {
  __shared__ float xs[GR][DIM];          // 16 KB (unused by hist blocks)
  const int tid = threadIdx.x;

  if (blockIdx.x >= GEMM_BLOCKS) {       // block-uniform branch
    const int i = (blockIdx.x - GEMM_BLOCKS) * 256 + tid;
    if (i < N_EDGES) atomicAdd(&deg[dst[i]], 1);
    return;
  }

  const int row0 = blockIdx.x * GR;

  // stage x tile: 32 rows * 32 float4 = 1024 float4, 4 per thread, coalesced
#pragma unroll
  for (int i = 0; i < 4; ++i) {
    const int idx = i * 256 + tid;       // 0..1023
    const int r = idx >> 5;              // 32 float4 per row
    const int c4 = idx & 31;
    const float4 v = *reinterpret_cast<const float4*>(
        x + (size_t)(row0 + r) * DIM + c4 * 4);
    *reinterpret_cast<float4*>(&xs[r][c4 * 4]) = v;
  }
  __syncthreads();

  const int cg = tid & 63;               // 0..63 column group
  const int rg = tid >> 6;               // 0..3 row group
  const int which = cg >> 5;             // 0 -> Wl, 1 -> Wr
  const int col0 = (cg & 31) * 4;        // 0..124
  const float* __restrict__ W = which ? Wr : Wl;
  const float* __restrict__ b = which ? br : bl;
  float* __restrict__ o = which ? xr : xl;
  const int r0 = rg * 8;

  float acc[8][4];
#pragma unroll
  for (int r = 0; r < 8; ++r)
#pragma unroll
    for (int c = 0; c < 4; ++c) acc[r][c] = 0.f;

  for (int kb = 0; kb < DIM; kb += 4) {
    float4 w0 = *reinterpret_cast<const float4*>(W + (kb + 0) * DIM + col0);
    float4 w1 = *reinterpret_cast<const float4*>(W + (kb + 1) * DIM + col0);
    float4 w2 = *reinterpret_cast<const float4*>(W + (kb + 2) * DIM + col0);
    float4 w3 = *reinterpret_cast<const float4*>(W + (kb + 3) * DIM + col0);
#pragma unroll
    for (int r = 0; r < 8; ++r) {
      const float4 xv = *reinterpret_cast<const float4*>(&xs[r0 + r][kb]);
      acc[r][0] = fmaf(xv.x, w0.x, acc[r][0]);
      acc[r][1] = fmaf(xv.x, w0.y, acc[r][1]);
      acc[r][2] = fmaf(xv.x, w0.z, acc[r][2]);
      acc[r][3] = fmaf(xv.x, w0.w, acc[r][3]);
      acc[r][0] = fmaf(xv.y, w1.x, acc[r][0]);
      acc[r][1] = fmaf(xv.y, w1.y, acc[r][1]);
      acc[r][2] = fmaf(xv.y, w1.z, acc[r][2]);
      acc[r][3] = fmaf(xv.y, w1.w, acc[r][3]);
      acc[r][0] = fmaf(xv.z, w2.x, acc[r][0]);
      acc[r][1] = fmaf(xv.z, w2.y, acc[r][1]);
      acc[r][2] = fmaf(xv.z, w2.z, acc[r][2]);
      acc[r][3] = fmaf(xv.z, w2.w, acc[r][3]);
      acc[r][0] = fmaf(xv.w, w3.x, acc[r][0]);
      acc[r][1] = fmaf(xv.w, w3.y, acc[r][1]);
      acc[r][2] = fmaf(xv.w, w3.z, acc[r][2]);
      acc[r][3] = fmaf(xv.w, w3.w, acc[r][3]);
    }
  }

  const float4 bb = *reinterpret_cast<const float4*>(b + col0);
#pragma unroll
  for (int r = 0; r < 8; ++r) {
    float4 ov;
    ov.x = acc[r][0] + bb.x;
    ov.y = acc[r][1] + bb.y;
    ov.z = acc[r][2] + bb.z;
    ov.w = acc[r][3] + bb.w;
    *reinterpret_cast<float4*>(o + (size_t)(row0 + r0 + r) * DIM + col0) = ov;
  }
}

// ---------------------------------------------------------------------------
// CSR build: block-level exclusive scan of deg, then scatter src ids.
// ---------------------------------------------------------------------------
__global__ __launch_bounds__(1024) void scan1(const int* __restrict__ deg,
                                              int* __restrict__ excl,
                                              int* __restrict__ bsum) {
  __shared__ int tmp[1024];
  const int tid = threadIdx.x;
  const int gid = blockIdx.x * 1024 + tid;
  const int v = (gid < N_NODES) ? deg[gid] : 0;
  int xacc = v;
  tmp[tid] = v;
  __syncthreads();
  for (int offd = 1; offd < 1024; offd <<= 1) {
    const int t = (tid >= offd) ? tmp[tid - offd] : 0;
    __syncthreads();
    xacc += t;
    tmp[tid] = xacc;
    __syncthreads();
  }
  if (gid < N_NODES) excl[gid] = xacc - v;       // exclusive within block
  if (tid == 1023) bsum[blockIdx.x] = xacc;      // block total
}

__global__ __launch_bounds__(128) void scan2(int* __restrict__ bsum, int nb) {
  __shared__ int tmp[128];
  const int tid = threadIdx.x;
  const int v = (tid < nb) ? bsum[tid] : 0;
  int xacc = v;
  tmp[tid] = v;
  __syncthreads();
  for (int offd = 1; offd < 128; offd <<= 1) {
    const int t = (tid >= offd) ? tmp[tid - offd] : 0;
    __syncthreads();
    xacc += t;
    tmp[tid] = xacc;
    __syncthreads();
  }
  if (tid < nb) bsum[tid] = xacc - v;            // exclusive block offsets
}

__global__ __launch_bounds__(1024) void scan3(int* __restrict__ offs,
                                              const int* __restrict__ bsum,
                                              int* __restrict__ fill) {
  const int gid = blockIdx.x * 1024 + threadIdx.x;
  if (gid < N_NODES) {
    const int o = offs[gid] + bsum[blockIdx.x];
    offs[gid] = o;
    fill[gid] = o;
  }
  if (gid == N_NODES) offs[N_NODES] = N_EDGES;
}

__global__ __launch_bounds__(256) void scatter_kernel(const int* __restrict__ src,
                                                      const int* __restrict__ dst,
                                                      int* __restrict__ fill,
                                                      int* __restrict__ csr) {
  const int i = blockIdx.x * 256 + threadIdx.x;
  if (i < N_EDGES) {
    const int slot = atomicAdd(&fill[dst[i]], 1);
    csr[slot] = src[i];
  }
}

// ---------------------------------------------------------------------------
// One wave per destination node, 4-way edge packing:
// lane = q*16 + i (q = edge slot 0..3, i = channel group). Lane owns 8
// channels c0 = 8i .. 8i+7, so 16 lanes cover a 128-ch row and the wave
// processes FOUR edges per iteration (slot q handles edges 4j+q of the
// 64-id chunk). Head = 32 ch = 4 lanes -> score reduce is 2 shfl_xor (1,2).
// Four independent online-softmax states (m, l, acc8), merged at the end
// via shfl_xor 16 then 32:  m* = max; l* = sum l_q e^{m_q - m*}; acc* same.
// Self loop lives in slot 0 only. Invalid slots: score -2e30 (< -1e30
// empty-state init -> exp underflows to 0) plus explicit w=0 select.
// Gather is software-pipelined depth 2 (named regs, no runtime indexing).
// xr lives in `out` (read before overwrite, same row only).
// ---------------------------------------------------------------------------
__global__ __launch_bounds__(256) void gat_node(
    const float* __restrict__ xl,
    const float* __restrict__ att, const float* __restrict__ bias,
    const int* __restrict__ offs, const int* __restrict__ csr,
    float* __restrict__ out) {
  const int wid = (blockIdx.x * 256 + threadIdx.x) >> 6;
  const int lane = threadIdx.x & 63;
  if (wid >= N_NODES) return;
  const int d = wid;
  const int q = lane >> 4;           // edge slot
  const int i = lane & 15;           // channel group
  const int c0 = i * 8;              // channel base

  const float4 aA = *reinterpret_cast<const float4*>(att + c0);
  const float4 aB = *reinterpret_cast<const float4*>(att + c0 + 4);
  const float4 rA = *reinterpret_cast<const float4*>(out + (size_t)d * DIM + c0);
  const float4 rB = *reinterpret_cast<const float4*>(out + (size_t)d * DIM + c0 + 4);
  const float4 sA = *reinterpret_cast<const float4*>(xl + (size_t)d * DIM + c0);
  const float4 sB = *reinterpret_cast<const float4*>(xl + (size_t)d * DIM + c0 + 4);

  // self-loop score (same value in every slot; only slot 0 keeps the state)
  float p = lr(sA.x + rA.x) * aA.x + lr(sA.y + rA.y) * aA.y
          + lr(sA.z + rA.z) * aA.z + lr(sA.w + rA.w) * aA.w
          + lr(sB.x + rB.x) * aB.x + lr(sB.y + rB.y) * aB.y
          + lr(sB.z + rB.z) * aB.z + lr(sB.w + rB.w) * aB.w;
  p += __shfl_xor(p, 1);
  p += __shfl_xor(p, 2);             // 4-lane head group holds its score

  const bool q0 = (q == 0);
  float m = q0 ? p : -1e30f;         // running max
  float l = q0 ? 1.f : 0.f;          // running denom
  float4 cA, cB;                     // running weighted message sum
  cA.x = q0 ? sA.x : 0.f;  cA.y = q0 ? sA.y : 0.f;
  cA.z = q0 ? sA.z : 0.f;  cA.w = q0 ? sA.w : 0.f;
  cB.x = q0 ? sB.x : 0.f;  cB.y = q0 ? sB.y : 0.f;
  cB.z = q0 ? sB.z : 0.f;  cB.w = q0 ? sB.w : 0.f;

  const int beg = offs[d];
  const int end = offs[d + 1];

  for (int cbase = beg; cbase < end; cbase += 64) {
    const int idx = cbase + lane;
    const int sv = csr[idx < end ? idx : end - 1];   // 64 edge ids, coalesced
    const int cnt = min(64, end - cbase);
    const int nj = (cnt + 3) >> 2;   // iterations; slot q handles edges 4j+q

    // prefetch j=0: slot q's first edge id is at position q
    const int s0 = __shfl(sv, q);
    const float* rp0 = xl + (size_t)s0 * DIM + c0;
    float4 nA = *reinterpret_cast<const float4*>(rp0);
    float4 nB = *reinterpret_cast<const float4*>(rp0 + 4);

    for (int j = 0; j < nj; ++j) {
      const float4 xA = nA;
      const float4 xB = nB;
      if (j + 1 < nj) {
        const int s1 = __shfl(sv, 4 * (j + 1) + q);  // <= 63 always
        const float* rp = xl + (size_t)s1 * DIM + c0;
        nA = *reinterpret_cast<const float4*>(rp);
        nB = *reinterpret_cast<const float4*>(rp + 4);
      }
      const bool valid = (4 * j + q) < cnt;

      float ek = lr(xA.x + rA.x) * aA.x + lr(xA.y + rA.y) * aA.y
               + lr(xA.z + rA.z) * aA.z + lr(xA.w + rA.w) * aA.w
               + lr(xB.x + rB.x) * aB.x + lr(xB.y + rB.y) * aB.y
               + lr(xB.z + rB.z) * aB.z + lr(xB.w + rB.w) * aB.w;
      ek += __shfl_xor(ek, 1);
      ek += __shfl_xor(ek, 2);
      ek = valid ? ek : -2e30f;

      const float mn = fmaxf(m, ek);
      const float sc = __expf(m - mn);
      float w = __expf(ek - mn);
      w = valid ? w : 0.f;
      l = l * sc + w;
      cA.x = fmaf(cA.x, sc, w * xA.x);
      cA.y = fmaf(cA.y, sc, w * xA.y);
      cA.z = fmaf(cA.z, sc, w * xA.z);
      cA.w = fmaf(cA.w, sc, w * xA.w);
      cB.x = fmaf(cB.x, sc, w * xB.x);
      cB.y = fmaf(cB.y, sc, w * xB.y);
      cB.z = fmaf(cB.z, sc, w * xB.z);
      cB.w = fmaf(cB.w, sc, w * xB.w);
      m = mn;
    }
  }

  // merge the four slots' states: xor 16 (q0<->q1, q2<->q3), then xor 32
  auto merge = [&](int mask) {
    const float mo = __shfl_xor(m, mask);
    const float lo = __shfl_xor(l, mask);
    float4 oA, oB;
    oA.x = __shfl_xor(cA.x, mask);  oA.y = __shfl_xor(cA.y, mask);
    oA.z = __shfl_xor(cA.z, mask);  oA.w = __shfl_xor(cA.w, mask);
    oB.x = __shfl_xor(cB.x, mask);  oB.y = __shfl_xor(cB.y, mask);
    oB.z = __shfl_xor(cB.z, mask);  oB.w = __shfl_xor(cB.w, mask);
    const float ms = fmaxf(m, mo);
    const float w1 = __expf(m - ms);
    const float w2 = __expf(mo - ms);
    l = l * w1 + lo * w2;
    cA.x = cA.x * w1 + oA.x * w2;  cA.y = cA.y * w1 + oA.y * w2;
    cA.z = cA.z * w1 + oA.z * w2;  cA.w = cA.w * w1 + oA.w * w2;
    cB.x = cB.x * w1 + oB.x * w2;  cB.y = cB.y * w1 + oB.y * w2;
    cB.z = cB.z * w1 + oB.z * w2;  cB.w = cB.w * w1 + oB.w * w2;
    m = ms;
  };
  merge(16);
  merge(32);

  if (lane < 16) {                   // slot 0 writes the result
    const float inv = 1.f / l;       // l >= e^{p - m*} > 0 (self loop)
    const float4 bA = *reinterpret_cast<const float4*>(bias + c0);
    const float4 bB = *reinterpret_cast<const float4*>(bias + c0 + 4);
    float4 oA, oB;
    oA.x = cA.x * inv + bA.x;  oA.y = cA.y * inv + bA.y;
    oA.z = cA.z * inv + bA.z;  oA.w = cA.w * inv + bA.w;
    oB.x = cB.x * inv + bB.x;  oB.y = cB.y * inv + bB.y;
    oB.z = cB.z * inv + bB.z;  oB.w = cB.w * inv + bB.w;
    *reinterpret_cast<float4*>(out + (size_t)d * DIM + c0) = oA;
    *reinterpret_cast<float4*>(out + (size_t)d * DIM + c0 + 4) = oB;
  }
}

// ---------------------------------------------------------------------------
extern "C" void kernel_launch(void* const* d_in, const int* in_sizes, int n_in,
                              void* d_out, int out_size, void* d_ws, size_t ws_size,
                              hipStream_t stream) {
  const float* x    = (const float*)d_in[0];
  const float* Wl   = (const float*)d_in[1];
  const float* bl   = (const float*)d_in[2];
  const float* Wr   = (const float*)d_in[3];
  const float* br   = (const float*)d_in[4];
  const float* att  = (const float*)d_in[5];
  const float* bias = (const float*)d_in[6];
  const int* src    = (const int*)d_in[7];
  const int* dst    = (const int*)d_in[8];
  float* out = (float*)d_out;

  char* w = (char*)d_ws;
  size_t off = 0;
  auto alloc = [&](size_t bytes) -> void* {
    void* p = w + off;
    off = (off + bytes + 255) & ~(size_t)255;
    return p;
  };
  float* xl = (float*)alloc((size_t)N_NODES * DIM * 4);   // 51.2 MB
  int* deg  = (int*)alloc((size_t)N_NODES * 4);
  int* offs = (int*)alloc((size_t)(N_NODES + 1) * 4);
  int* fill = (int*)alloc((size_t)N_NODES * 4);
  int* bsum = (int*)alloc(1024);
  int* csr  = (int*)alloc((size_t)N_EDGES * 4);           // 6.4 MB
  float* xr = out;                                        // scratch alias (safe: see gat_node)

  const int nscan_blocks = (N_NODES + 1023) / 1024;   // 98

  hipMemsetAsync(deg, 0, (size_t)N_NODES * 4, stream);
  gemm_hist<<<GEMM_BLOCKS + HIST_BLOCKS, 256, 0, stream>>>(
      x, Wl, bl, Wr, br, xl, xr, dst, deg);
  scan1<<<nscan_blocks, 1024, 0, stream>>>(deg, offs, bsum);
  scan2<<<1, 128, 0, stream>>>(bsum, nscan_blocks);
  scan3<<<nscan_blocks, 1024, 0, stream>>>(offs, bsum, fill);
  scatter_kernel<<<(N_EDGES + 255) / 256, 256, 0, stream>>>(src, dst, fill, csr);
  gat_node<<<(N_NODES * 64 + 255) / 256, 256, 0, stream>>>(xl, att, bias, offs, csr, out);
}